// Round 9
// baseline (101.262 us; speedup 1.0000x reference)
//
#include <hip/hip_runtime.h>
#include <hip/hip_bf16.h>

// out[4096,128] = bias + P @ W; P[r][k] = prod of x[r, subset_k], subsets are
// ALL k-combinations of range(32) in lexicographic order -> compile-time schedule.
// Block = 64 rows x 32 cols; waves = {rowtile0,rowtile1} x {khalf0,khalf1}.
// The two rowtile-waves of a K-half read the SAME B-frag stream (L1 reuse).
// LDS fp32 reduce across K-halves -> direct out write. No fences, no atomics.
constexpr int B_   = 4096;
constexpr int C_   = 128;
constexpr int K1   = 32;
constexpr int K2   = 496;
constexpr int K3   = 4960;
constexpr int KTOT = K1 + K2 + K3;    // 5488 = 343 * 16 exactly -> no pad chunks
constexpr int NCH  = KTOT / 16;       // 343 chunks of K=16
constexpr int CHSPLIT = 172;          // khalf0: [0,172), khalf1: [172,343)

typedef __attribute__((ext_vector_type(8)))  short bf16x8;
typedef __attribute__((ext_vector_type(16))) float f32x16;

// ws layout
constexpr size_t WS_WT = 0;   // swizzled bf16 W: 343 chunks * 4 ct * 64 lanes * 16B = 1404928 B

// ---- compile-time subset schedule (lexicographic combinations; idx 32 -> xv[32]=1.0) ----
struct Sched { short a[KTOT]; short b[KTOT]; short c[KTOT]; };
constexpr Sched make_sched() {
    Sched s{}; int k = 0;
    for (int i = 0; i < 32; ++i) { s.a[k] = i; s.b[k] = 32; s.c[k] = 32; ++k; }
    for (int i = 0; i < 32; ++i)
        for (int j = i + 1; j < 32; ++j) { s.a[k] = i; s.b[k] = j; s.c[k] = 32; ++k; }
    for (int i = 0; i < 32; ++i)
        for (int j = i + 1; j < 32; ++j)
            for (int l = j + 1; l < 32; ++l) { s.a[k] = i; s.b[k] = j; s.c[k] = l; ++k; }
    return s;
}
constexpr Sched SCH = make_sched();

template<int K>
__device__ __forceinline__ float prodK(const float (&xv)[33]) {
    return xv[SCH.a[K]] * xv[SCH.b[K]] * xv[SCH.c[K]];   // static reg indices; pab CSE'd
}

template<int K0, int J>
__device__ __forceinline__ void prods8(const float (&xv)[33], bool hi, float (&q)[8]) {
    if constexpr (J < 8) {
        q[J] = hi ? prodK<K0 + 8 + J>(xv) : prodK<K0 + J>(xv);   // kg select
        prods8<K0, J + 1>(xv, hi, q);
    }
}

// chunks [CH, CHEND) for one rowtile / one col-tile
template<int CH, int CHEND>
__device__ __forceinline__ void run_chunks(const float (&xv)[33], bool hi, int lane, int ct,
                                           const ushort* __restrict__ Wb, f32x16& acc) {
    if constexpr (CH < CHEND) {
        constexpr int K0 = CH * 16;
        // B-frag from L2/L1-resident swizzled table: 1KB coalesced per wave-load;
        // the partner rowtile-wave reads the same line moments later -> L1 hit.
        bf16x8 b0 = *(const bf16x8*)(Wb + ((size_t)(CH * 4 + ct) * 64 + lane) * 8);
        // A-frag: lane's own 8 products, pure register VALU
        float q[8];
        prods8<K0, 0>(xv, hi, q);
        union { ushort us[8]; bf16x8 v; } af;
        #pragma unroll
        for (int j = 0; j < 8; ++j) {
            __hip_bfloat16 h = __float2bfloat16(q[j]);
            af.us[j] = *reinterpret_cast<ushort*>(&h);
        }
        acc = __builtin_amdgcn_mfma_f32_32x32x16_bf16(af.v, b0, acc, 0, 0, 0);
        run_chunks<CH + 1, CHEND>(xv, hi, lane, ct, Wb, acc);
    }
}

// prep: W (fp32 [k][c]) -> swizzled bf16 B-frag table matching the wave load pattern
__global__ __launch_bounds__(256)
void prep_wt(const float* __restrict__ W1,
             const float* __restrict__ W2,
             const float* __restrict__ W3,
             ushort* __restrict__ Wb)
{
    __shared__ ushort tile[16 * 130];
    const int gc = blockIdx.x, t = threadIdx.x;
    const int k0 = gc * 16;
    #pragma unroll
    for (int p = 0; p < 2; ++p) {
        int e  = p * 256 + t;                 // 512 float4 groups = 16k x 32cq
        int kk = e >> 5, cq = e & 31;
        int k  = k0 + kk;
        float4 v = {0.f, 0.f, 0.f, 0.f};
        if (k < K1)           v = ((const float4*)W1)[k * 32 + cq];
        else if (k < K1 + K2) v = ((const float4*)W2)[(k - K1) * 32 + cq];
        else if (k < KTOT)    v = ((const float4*)W3)[(k - K1 - K2) * 32 + cq];
        union { ushort u[4]; uint2 d; } o;
        __hip_bfloat16 h0 = __float2bfloat16(v.x); o.u[0] = *(ushort*)&h0;
        __hip_bfloat16 h1 = __float2bfloat16(v.y); o.u[1] = *(ushort*)&h1;
        __hip_bfloat16 h2 = __float2bfloat16(v.z); o.u[2] = *(ushort*)&h2;
        __hip_bfloat16 h3 = __float2bfloat16(v.w); o.u[3] = *(ushort*)&h3;
        *(uint2*)&tile[kk * 130 + cq * 4] = o.d;
    }
    __syncthreads();
    {
        int ct = t >> 6, lane = t & 63, n = lane & 31, kg = lane >> 5;
        union { ushort us[8]; uint4 d; } o;
        #pragma unroll
        for (int j = 0; j < 8; ++j) o.us[j] = tile[(kg * 8 + j) * 130 + ct * 32 + n];
        *(uint4*)&Wb[((size_t)(gc * 4 + ct) * 64 + lane) * 8] = o.d;
    }
}

// main: 64 rows x 32 cols; waves = 2 rowtiles x 2 K-halves; LDS fp32 reduce
__global__ __launch_bounds__(256, 2)
void poly_mfma(const float* __restrict__ x,
               const ushort* __restrict__ Wb,
               const float* __restrict__ bias,
               float* __restrict__ out)
{
    __shared__ float red[4][32 * 33];     // per-wave accs; stride 33 -> conflict-free

    const int t    = threadIdx.x;
    const int lane = t & 63;
    const int w    = t >> 6;
    const int rt   = w & 1;               // rowtile 0/1
    const int m    = lane & 31;           // A row lane index
    const bool hi  = lane >= 32;          // kg
    const int row0 = blockIdx.x * 64;
    const int ct   = blockIdx.y;          // col tile: cols [ct*32, ct*32+32)

    // lane's row -> 33 statically-indexed VGPRs (xv[32]=1.0 handles order<3)
    float xv[33];
    {
        const float4* xrow = (const float4*)(x + (size_t)(row0 + rt * 32 + m) * 32);
        #pragma unroll
        for (int qv = 0; qv < 8; ++qv) {
            float4 v = xrow[qv];
            xv[qv * 4 + 0] = v.x; xv[qv * 4 + 1] = v.y;
            xv[qv * 4 + 2] = v.z; xv[qv * 4 + 3] = v.w;
        }
        xv[32] = 1.0f;
    }

    f32x16 acc;
    #pragma unroll
    for (int i = 0; i < 16; ++i) acc[i] = 0.f;

    // waves 0,1: K-half 0 (rowtiles 0,1 share the B stream -> L1 reuse)
    // waves 2,3: K-half 1
    if (w < 2) run_chunks<0, CHSPLIT>(xv, hi, lane, ct, Wb, acc);
    else       run_chunks<CHSPLIT, NCH>(xv, hi, lane, ct, Wb, acc);

    // C/D layout (verified): col = lane&31, row = (e&3) + 8*(e>>2) + 4*kg
    const int kg = hi ? 1 : 0;
    #pragma unroll
    for (int e = 0; e < 16; ++e) {
        int r = (e & 3) + 8 * (e >> 2) + 4 * kg;
        red[w][r * 33 + m] = acc[e];
    }
    __syncthreads();

    // out = bias + khalf0 + khalf1 (exact fp32, fixed order); 8 outputs/thread
    {
        int r  = t >> 2;                  // 64 rows, 4 threads/row
        int c0 = (t & 3) * 8;             // 8 cols each
        int rtile = r >> 5, rr = r & 31;
        float s[8];
        #pragma unroll
        for (int j = 0; j < 8; ++j) {
            float b = bias[ct * 32 + c0 + j];
            s[j] = b + red[rtile][rr * 33 + c0 + j] + red[rtile + 2][rr * 33 + c0 + j];
        }
        float4 o0 = {s[0], s[1], s[2], s[3]};
        float4 o1 = {s[4], s[5], s[6], s[7]};
        float* op = &out[(size_t)(row0 + r) * C_ + ct * 32 + c0];
        *(float4*)op       = o0;
        *(float4*)(op + 4) = o1;
    }
}

extern "C" void kernel_launch(void* const* d_in, const int* in_sizes, int n_in,
                              void* d_out, int out_size, void* d_ws, size_t ws_size,
                              hipStream_t stream)
{
    const float* x    = (const float*)d_in[0];
    const float* bias = (const float*)d_in[1];
    const float* W1   = (const float*)d_in[2];
    const float* W2   = (const float*)d_in[3];
    const float* W3   = (const float*)d_in[4];
    // idx1/idx2/idx3 (d_in[5..7]) are deterministic lexicographic combinations -> baked at compile time
    float* out = (float*)d_out;

    ushort* Wb = (ushort*)((char*)d_ws + WS_WT);

    prep_wt<<<NCH, 256, 0, stream>>>(W1, W2, W3, Wb);   // 343 blocks

    dim3 grid(B_ / 64, C_ / 32);          // 64 x 4 = 256 blocks = 1/CU
    poly_mfma<<<grid, 256, 0, stream>>>(x, Wb, bias, out);
}

// Round 10
// 82.651 us; speedup vs baseline: 1.2252x; 1.2252x over previous
//
#include <hip/hip_runtime.h>
#include <hip/hip_bf16.h>

// out[4096,128] = bias + P @ W; P[r][k] = prod of x[r, subset_k], subsets are
// ALL k-combinations of range(32) in lexicographic order -> compile-time schedule.
// Block = 64 rows x 32 cols, 512 threads = 8 waves = 2 rowtiles x 4 K-quarters.
// The two rowtile-waves of a K-quarter read the SAME B-frag stream -> L1 reuse,
// while 8 waves/CU keeps 2 waves/SIMD for latency hiding (R8's proven occupancy).
// LDS fp32 reduce across K-quarters -> direct out write. No fences, no atomics.
constexpr int B_   = 4096;
constexpr int C_   = 128;
constexpr int K1   = 32;
constexpr int K2   = 496;
constexpr int K3   = 4960;
constexpr int KTOT = K1 + K2 + K3;    // 5488 = 343 * 16 exactly -> no pad chunks
constexpr int NCH  = KTOT / 16;       // 343 chunks of K=16
// K-quarter chunk ranges: [0,86), [86,172), [172,258), [258,343)
constexpr int Q0 = 0, Q1 = 86, Q2 = 172, Q3 = 258, Q4 = NCH;

typedef __attribute__((ext_vector_type(8)))  short bf16x8;
typedef __attribute__((ext_vector_type(16))) float f32x16;

// ws layout
constexpr size_t WS_WT = 0;   // swizzled bf16 W: 343 chunks * 4 ct * 64 lanes * 16B = 1404928 B

// ---- compile-time subset schedule (lexicographic combinations; idx 32 -> xv[32]=1.0) ----
struct Sched { short a[KTOT]; short b[KTOT]; short c[KTOT]; };
constexpr Sched make_sched() {
    Sched s{}; int k = 0;
    for (int i = 0; i < 32; ++i) { s.a[k] = i; s.b[k] = 32; s.c[k] = 32; ++k; }
    for (int i = 0; i < 32; ++i)
        for (int j = i + 1; j < 32; ++j) { s.a[k] = i; s.b[k] = j; s.c[k] = 32; ++k; }
    for (int i = 0; i < 32; ++i)
        for (int j = i + 1; j < 32; ++j)
            for (int l = j + 1; l < 32; ++l) { s.a[k] = i; s.b[k] = j; s.c[k] = l; ++k; }
    return s;
}
constexpr Sched SCH = make_sched();

template<int K>
__device__ __forceinline__ float prodK(const float (&xv)[33]) {
    return xv[SCH.a[K]] * xv[SCH.b[K]] * xv[SCH.c[K]];   // static reg indices; pab CSE'd
}

template<int K0, int J>
__device__ __forceinline__ void prods8(const float (&xv)[33], bool hi, float (&q)[8]) {
    if constexpr (J < 8) {
        q[J] = hi ? prodK<K0 + 8 + J>(xv) : prodK<K0 + J>(xv);   // kg select
        prods8<K0, J + 1>(xv, hi, q);
    }
}

// chunks [CH, CHEND) for one rowtile / one col-tile
template<int CH, int CHEND>
__device__ __forceinline__ void run_chunks(const float (&xv)[33], bool hi, int lane, int ct,
                                           const ushort* __restrict__ Wb, f32x16& acc) {
    if constexpr (CH < CHEND) {
        constexpr int K0 = CH * 16;
        // B-frag from the swizzled table: 1KB coalesced per wave-load; the partner
        // rowtile-wave reads the same lines moments later -> per-CU L1 hit.
        bf16x8 b0 = *(const bf16x8*)(Wb + ((size_t)(CH * 4 + ct) * 64 + lane) * 8);
        // A-frag: lane's own 8 products, pure register VALU
        float q[8];
        prods8<K0, 0>(xv, hi, q);
        union { ushort us[8]; bf16x8 v; } af;
        #pragma unroll
        for (int j = 0; j < 8; ++j) {
            __hip_bfloat16 h = __float2bfloat16(q[j]);
            af.us[j] = *reinterpret_cast<ushort*>(&h);
        }
        acc = __builtin_amdgcn_mfma_f32_32x32x16_bf16(af.v, b0, acc, 0, 0, 0);
        run_chunks<CH + 1, CHEND>(xv, hi, lane, ct, Wb, acc);
    }
}

// prep: W (fp32 [k][c]) -> swizzled bf16 B-frag table matching the wave load pattern
__global__ __launch_bounds__(256)
void prep_wt(const float* __restrict__ W1,
             const float* __restrict__ W2,
             const float* __restrict__ W3,
             ushort* __restrict__ Wb)
{
    __shared__ ushort tile[16 * 130];
    const int gc = blockIdx.x, t = threadIdx.x;
    const int k0 = gc * 16;
    #pragma unroll
    for (int p = 0; p < 2; ++p) {
        int e  = p * 256 + t;                 // 512 float4 groups = 16k x 32cq
        int kk = e >> 5, cq = e & 31;
        int k  = k0 + kk;
        float4 v = {0.f, 0.f, 0.f, 0.f};
        if (k < K1)           v = ((const float4*)W1)[k * 32 + cq];
        else if (k < K1 + K2) v = ((const float4*)W2)[(k - K1) * 32 + cq];
        else if (k < KTOT)    v = ((const float4*)W3)[(k - K1 - K2) * 32 + cq];
        union { ushort u[4]; uint2 d; } o;
        __hip_bfloat16 h0 = __float2bfloat16(v.x); o.u[0] = *(ushort*)&h0;
        __hip_bfloat16 h1 = __float2bfloat16(v.y); o.u[1] = *(ushort*)&h1;
        __hip_bfloat16 h2 = __float2bfloat16(v.z); o.u[2] = *(ushort*)&h2;
        __hip_bfloat16 h3 = __float2bfloat16(v.w); o.u[3] = *(ushort*)&h3;
        *(uint2*)&tile[kk * 130 + cq * 4] = o.d;
    }
    __syncthreads();
    {
        int ct = t >> 6, lane = t & 63, n = lane & 31, kg = lane >> 5;
        union { ushort us[8]; uint4 d; } o;
        #pragma unroll
        for (int j = 0; j < 8; ++j) o.us[j] = tile[(kg * 8 + j) * 130 + ct * 32 + n];
        *(uint4*)&Wb[((size_t)(gc * 4 + ct) * 64 + lane) * 8] = o.d;
    }
}

// main: 64 rows x 32 cols, 8 waves = 2 rowtiles x 4 K-quarters; LDS fp32 reduce
__global__ __launch_bounds__(512, 2)
void poly_mfma(const float* __restrict__ x,
               const ushort* __restrict__ Wb,
               const float* __restrict__ bias,
               float* __restrict__ out)
{
    __shared__ float red[8][32 * 33];     // per-wave accs; stride 33 -> conflict-free

    const int t    = threadIdx.x;
    const int lane = t & 63;
    const int w    = t >> 6;              // wave id 0..7
    const int kq   = w & 3;               // K-quarter
    const int rt   = w >> 2;              // rowtile 0/1
    const int m    = lane & 31;           // A row lane index
    const bool hi  = lane >= 32;          // kg
    const int row0 = blockIdx.x * 64;
    const int ct   = blockIdx.y;          // col tile: cols [ct*32, ct*32+32)

    // lane's row -> 33 statically-indexed VGPRs (xv[32]=1.0 handles order<3)
    float xv[33];
    {
        const float4* xrow = (const float4*)(x + (size_t)(row0 + rt * 32 + m) * 32);
        #pragma unroll
        for (int qv = 0; qv < 8; ++qv) {
            float4 v = xrow[qv];
            xv[qv * 4 + 0] = v.x; xv[qv * 4 + 1] = v.y;
            xv[qv * 4 + 2] = v.z; xv[qv * 4 + 3] = v.w;
        }
        xv[32] = 1.0f;
    }

    f32x16 acc;
    #pragma unroll
    for (int i = 0; i < 16; ++i) acc[i] = 0.f;

    switch (kq) {
        case 0:  run_chunks<Q0, Q1>(xv, hi, lane, ct, Wb, acc); break;
        case 1:  run_chunks<Q1, Q2>(xv, hi, lane, ct, Wb, acc); break;
        case 2:  run_chunks<Q2, Q3>(xv, hi, lane, ct, Wb, acc); break;
        default: run_chunks<Q3, Q4>(xv, hi, lane, ct, Wb, acc); break;
    }

    // C/D layout (verified): col = lane&31, row = (e&3) + 8*(e>>2) + 4*kg
    const int kg = hi ? 1 : 0;
    #pragma unroll
    for (int e = 0; e < 16; ++e) {
        int r = (e & 3) + 8 * (e >> 2) + 4 * kg;
        red[w][r * 33 + m] = acc[e];
    }
    __syncthreads();

    // out = bias + kq0 + kq1 + kq2 + kq3 (exact fp32, fixed order); 4 outputs/thread
    {
        int r  = t >> 3;                  // 64 rows, 8 threads/row
        int c0 = (t & 7) * 4;             // 4 cols each
        int rtile = r >> 5, rr = r & 31;
        float4 b = *(const float4*)&bias[ct * 32 + c0];
        float s[4] = {b.x, b.y, b.z, b.w};
        #pragma unroll
        for (int q = 0; q < 4; ++q)
            #pragma unroll
            for (int j = 0; j < 4; ++j)
                s[j] += red[rtile * 4 + q][rr * 33 + c0 + j];
        float4 o = {s[0], s[1], s[2], s[3]};
        *(float4*)&out[(size_t)(row0 + r) * C_ + ct * 32 + c0] = o;
    }
}

extern "C" void kernel_launch(void* const* d_in, const int* in_sizes, int n_in,
                              void* d_out, int out_size, void* d_ws, size_t ws_size,
                              hipStream_t stream)
{
    const float* x    = (const float*)d_in[0];
    const float* bias = (const float*)d_in[1];
    const float* W1   = (const float*)d_in[2];
    const float* W2   = (const float*)d_in[3];
    const float* W3   = (const float*)d_in[4];
    // idx1/idx2/idx3 (d_in[5..7]) are deterministic lexicographic combinations -> baked at compile time
    float* out = (float*)d_out;

    ushort* Wb = (ushort*)((char*)d_ws + WS_WT);

    prep_wt<<<NCH, 256, 0, stream>>>(W1, W2, W3, Wb);   // 343 blocks

    dim3 grid(B_ / 64, C_ / 32);          // 64 x 4 = 256 blocks, 512 thr = 8 waves/CU
    poly_mfma<<<grid, 512, 0, stream>>>(x, Wb, bias, out);
}